// Round 5
// baseline (46.191 us; speedup 1.0000x reference)
//
#include <hip/hip_runtime.h>

#define B 16
#define ENC_T 512
#define ENC_DIM 512
#define DEC_T 2048
#define RPB 32                        // decoder rows per block
#define NB_HALF (B * DEC_T / RPB)     // 1024 blocks per output tensor
#define NBLK (2 * NB_HALF)            // 2048 total

// Specialized writer: blocks [0,1024) stream `out` (gather), [1024,2048) stream `att`
// (pure one-hot store, no global loads). Each block covers a 64KB contiguous span.
__global__ __launch_bounds__(512) void writer_kernel(const float* __restrict__ enc,
                                                     const float* __restrict__ enc_len,
                                                     float* __restrict__ out,
                                                     float* __restrict__ att) {
    __shared__ short segl[RPB];
    __shared__ int wsum[8];

    const int bid   = blockIdx.x;
    const bool isAtt = bid >= NB_HALF;
    const int wb    = isAtt ? bid - NB_HALF : bid;   // 0..1023
    const int b     = wb >> 6;                       // 64 blocks per batch
    const int w0    = (wb & 63) * RPB;               // first decoder row of window
    const int tid   = threadIdx.x;                   // 0..511

    if (tid < RPB) segl[tid] = -1;

    // ---- per-block redundant cumsum of batch durations (shfl scan) ----
    int v = (int)enc_len[(size_t)b * ENC_T + tid];   // small ints, exact in f32
    const int len  = v;
    const int lane = tid & 63;
    #pragma unroll
    for (int off = 1; off < 64; off <<= 1) {
        int u = __shfl_up(v, off, 64);
        if (lane >= off) v += u;
    }
    const int w = tid >> 6;
    if (lane == 63) wsum[w] = v;
    __syncthreads();                                 // wsum ready; segl init done
    int woff = 0;
    for (int k = 0; k < w; ++k) woff += wsum[k];
    const int end   = v + woff;                      // exclusive end of phoneme tid
    const int start = end - len;

    // ---- direct interval expansion into this block's 32-row window ----
    const int lo = start > w0 ? start : w0;
    const int hi = end < w0 + RPB ? end : w0 + RPB;
    for (int t = lo; t < hi; ++t) segl[t - w0] = (short)tid;   // distinct addrs
    __syncthreads();

    // ---- streaming phase: 4 rows at a time, 8KB contiguous per iteration ----
    const int r = tid >> 7;          // 0..3 (row within quad)
    const int j = tid & 127;         // float4 index within row
    if (!isAtt) {
        const float4* encb = (const float4*)(enc + (size_t)b * ENC_T * ENC_DIM);
        float4* ob = (float4*)(out + ((size_t)b * DEC_T + w0) * ENC_DIM);
        #pragma unroll
        for (int rr = 0; rr < RPB; rr += 4) {
            const int row = rr + r;
            const int s = segl[row];
            float4 o = make_float4(0.f, 0.f, 0.f, 0.f);
            if (s >= 0) o = encb[s * 128 + j];
            ob[row * 128 + j] = o;
        }
    } else {
        float4* ab = (float4*)(att + ((size_t)b * DEC_T + w0) * ENC_T);
        const int e0 = j << 2;
        #pragma unroll
        for (int rr = 0; rr < RPB; rr += 4) {
            const int row = rr + r;
            const int s = segl[row];
            float4 a = make_float4(0.f, 0.f, 0.f, 0.f);
            if (s >= e0 && s < e0 + 4) ((float*)&a)[s - e0] = 1.0f;
            ab[row * 128 + j] = a;
        }
    }
}

extern "C" void kernel_launch(void* const* d_in, const int* in_sizes, int n_in,
                              void* d_out, int out_size, void* d_ws, size_t ws_size,
                              hipStream_t stream) {
    const float* enc     = (const float*)d_in[0];   // [B, ENC_T, ENC_DIM]
    const float* enc_len = (const float*)d_in[2];   // [B, ENC_T]

    float* out = (float*)d_out;                          // [B, DEC_T, ENC_DIM]
    float* att = out + (size_t)B * DEC_T * ENC_DIM;      // [B, DEC_T, ENC_T]

    hipLaunchKernelGGL(writer_kernel, dim3(NBLK), dim3(512), 0, stream,
                       enc, enc_len, out, att);
}